// Round 1
// baseline (43.712 us; speedup 1.0000x reference)
//
#include <hip/hip_runtime.h>

#define IMG   512
#define QUADS (IMG / 4)   // 128 float4-quads per row

// tanh(v) = 1 - 2/(exp(2v)+1); exp via fast native path, rcp via v_rcp_f32.
// Handles saturation correctly: e->inf => 1, e->0 => -1.
__device__ __forceinline__ float fast_tanh(float v) {
    float e = __expf(2.0f * v);
    float r = __builtin_amdgcn_rcpf(e + 1.0f);
    return 1.0f - 2.0f * r;
}

__global__ __launch_bounds__(256) void fused_convtap_kernel(
    const float* __restrict__ x,   // (B,1,512,512)
    const float* __restrict__ W,   // (9,1,3,3)
    const float* __restrict__ Bv,  // (9,)
    float* __restrict__ out)       // (B,1,512,512)
{
    const int tid = blockIdx.x * 256 + threadIdx.x;
    const int xq  = tid & (QUADS - 1);
    const int row = tid >> 7;             // b*IMG + y
    const int y   = row & (IMG - 1);
    const int x0  = xq << 2;

    const float* xr = x + (size_t)row * IMG;   // row (b, y)

    // Uniform weights/bias -> compiler emits scalar loads (SGPR-resident).
    float w[81];
#pragma unroll
    for (int k = 0; k < 81; ++k) w[k] = W[k];
    float bv[9];
#pragma unroll
    for (int c = 0; c < 9; ++c) bv[c] = Bv[c];

    // Three input rows, columns x0-1 .. x0+4 (zero-padded outside image).
    float r0[6], r1[6], r2[6];
    const bool has_l = (x0 > 0);
    const bool has_r = (x0 < IMG - 4);

    if (y > 0) {
        const float* p = xr - IMG;
        float4 c = *reinterpret_cast<const float4*>(p + x0);
        r0[1] = c.x; r0[2] = c.y; r0[3] = c.z; r0[4] = c.w;
        r0[0] = has_l ? p[x0 - 1] : 0.0f;
        r0[5] = has_r ? p[x0 + 4] : 0.0f;
    } else {
        r0[0] = r0[1] = r0[2] = r0[3] = r0[4] = r0[5] = 0.0f;
    }
    {
        const float* p = xr;
        float4 c = *reinterpret_cast<const float4*>(p + x0);
        r1[1] = c.x; r1[2] = c.y; r1[3] = c.z; r1[4] = c.w;
        r1[0] = has_l ? p[x0 - 1] : 0.0f;
        r1[5] = has_r ? p[x0 + 4] : 0.0f;
    }
    if (y < IMG - 1) {
        const float* p = xr + IMG;
        float4 c = *reinterpret_cast<const float4*>(p + x0);
        r2[1] = c.x; r2[2] = c.y; r2[3] = c.z; r2[4] = c.w;
        r2[0] = has_l ? p[x0 - 1] : 0.0f;
        r2[5] = has_r ? p[x0 + 4] : 0.0f;
    } else {
        r2[0] = r2[1] = r2[2] = r2[3] = r2[4] = r2[5] = 0.0f;
    }

    // All indices below are compile-time constants after unrolling ->
    // everything stays in registers (no scratch, rule #20 safe).
#define ROW(p, idx) ((p) == 0 ? r0[idx] : (p) == 1 ? r1[idx] : r2[idx])

    float o[4];
#pragma unroll
    for (int t = 0; t < 4; ++t) {
        float acc = 0.0f;
#pragma unroll
        for (int i = 0; i < 3; ++i) {
#pragma unroll
            for (int j = 0; j < 3; ++j) {
                const int c = 3 * i + j;
                float fc = bv[c];
#pragma unroll
                for (int p = 0; p < 3; ++p) {
#pragma unroll
                    for (int q = 0; q < 3; ++q) {
                        fc = fmaf(ROW(p, t + q), w[c * 9 + p * 3 + q], fc);
                    }
                }
                acc = fmaf(ROW(j, t + i), fast_tanh(fc), acc);
            }
        }
        o[t] = acc;
    }
#undef ROW

    float4 ov = make_float4(o[0], o[1], o[2], o[3]);
    *reinterpret_cast<float4*>(out + (size_t)row * IMG + x0) = ov;
}

extern "C" void kernel_launch(void* const* d_in, const int* in_sizes, int n_in,
                              void* d_out, int out_size, void* d_ws, size_t ws_size,
                              hipStream_t stream) {
    const float* x  = (const float*)d_in[0];   // (B,1,512,512) f32
    const float* W  = (const float*)d_in[1];   // (9,1,3,3)     f32
    const float* Bv = (const float*)d_in[2];   // (9,)          f32

    float* out = (float*)d_out;

    const int batch   = in_sizes[0] / (IMG * IMG);       // 32
    const int threads = batch * IMG * QUADS;             // 2,097,152
    const int block   = 256;
    const int grid    = threads / block;                 // 8192

    fused_convtap_kernel<<<grid, block, 0, stream>>>(x, W, Bv, out);
}